// Round 4
// baseline (845.730 us; speedup 1.0000x reference)
//
#include <hip/hip_runtime.h>

// GraphSAGE 3-layer, N=50000, E=1.6M, D=128.
// R4: split aggregate (wave/node, high occupancy) + combine (VALU GEMM),
//     multi-block scan, weights repacked [k4][j][4].

constexpr int N_NODES = 50000;
constexpr int N_EDGES = 1600000;
constexpr int D = 128;
constexpr int NPB = 16;                       // nodes per combine block
constexpr int SCAN_BLK = 1024;
constexpr int NCHUNK = (N_NODES + SCAN_BLK - 1) / SCAN_BLK;  // 49

// ---------------- zero counts + cursor ----------------------------------
__global__ void zero_ints(int* __restrict__ a, int* __restrict__ b, int n) {
    int i = blockIdx.x * blockDim.x + threadIdx.x;
    if (i < n) { a[i] = 0; b[i] = 0; }
}

// ---------------- histogram of dst --------------------------------------
__global__ void hist_kernel(const int* __restrict__ dst, int* __restrict__ counts, int n) {
    int e = blockIdx.x * blockDim.x + threadIdx.x;
    if (e < n) atomicAdd(&counts[dst[e]], 1);
}

// ---------------- scan phase 1: per-chunk local scan ---------------------
__global__ __launch_bounds__(SCAN_BLK) void scan_p1(const int* __restrict__ counts,
                                                    int* __restrict__ row_ptr,
                                                    float* __restrict__ inv_deg,
                                                    int* __restrict__ blocksums) {
    __shared__ int wsum[16];
    __shared__ int wpre[16];
    const int t = threadIdx.x;
    const int i = blockIdx.x * SCAN_BLK + t;
    const int lane = t & 63, w = t >> 6;
    int v = (i < N_NODES) ? counts[i] : 0;
    int x = v;
    #pragma unroll
    for (int off = 1; off < 64; off <<= 1) {
        int tt = __shfl_up(x, off, 64);
        if (lane >= off) x += tt;
    }
    if (lane == 63) wsum[w] = x;
    __syncthreads();
    if (t < 16) {
        int s = wsum[t];
        int y = s;
        #pragma unroll
        for (int off = 1; off < 16; off <<= 1) {
            int tt = __shfl_up(y, off, 64);
            if (t >= off) y += tt;
        }
        wpre[t] = y - s;
    }
    __syncthreads();
    if (i < N_NODES) {
        row_ptr[i] = wpre[w] + (x - v);        // chunk-local exclusive
        inv_deg[i] = 1.0f / fmaxf((float)v, 1.0f);
    }
    if (t == SCAN_BLK - 1) blocksums[blockIdx.x] = wpre[15] + wsum[15];
}

// ---------------- scan phase 2: scan chunk totals (1 wave) ---------------
__global__ void scan_p2(const int* __restrict__ blocksums, int* __restrict__ blockoffs) {
    const int t = threadIdx.x;  // 64 threads
    int v = (t < NCHUNK) ? blocksums[t] : 0;
    int x = v;
    #pragma unroll
    for (int off = 1; off < 64; off <<= 1) {
        int tt = __shfl_up(x, off, 64);
        if (t >= off) x += tt;
    }
    if (t < NCHUNK) blockoffs[t] = x - v;
}

// ---------------- scan phase 3: add chunk offsets ------------------------
__global__ __launch_bounds__(SCAN_BLK) void scan_p3(int* __restrict__ row_ptr,
                                                    const int* __restrict__ blockoffs) {
    const int i = blockIdx.x * SCAN_BLK + threadIdx.x;
    if (i < N_NODES) row_ptr[i] += blockoffs[blockIdx.x];
    if (i == 0) row_ptr[N_NODES] = N_EDGES;
}

// ---------------- bucket edges by dst ------------------------------------
__global__ void bucket_kernel(const int* __restrict__ src, const int* __restrict__ dst,
                              const int* __restrict__ row_ptr, int* __restrict__ cursor,
                              int* __restrict__ esrc, int n) {
    int e = blockIdx.x * blockDim.x + threadIdx.x;
    if (e < n) {
        int d = dst[e];
        int pos = atomicAdd(&cursor[d], 1);
        esrc[row_ptr[d] + pos] = src[e];
    }
}

// ---------------- repack 6 weight matrices to [k4][j][4] ------------------
// Wq[(k>>2)*(D*4) + j*4 + (k&3)] = W[j][k]  -> combine loads float4 per k4.
__global__ void repack6(const float* __restrict__ w0, const float* __restrict__ w1,
                        const float* __restrict__ w2, const float* __restrict__ w3,
                        const float* __restrict__ w4, const float* __restrict__ w5,
                        float* __restrict__ outbase) {
    const float* ws[6] = {w0, w1, w2, w3, w4, w5};
    const float* w = ws[blockIdx.y];
    float* o = outbase + (size_t)blockIdx.y * D * D;
    int j = blockIdx.x;
    int k = threadIdx.x;
    o[(k >> 2) * (D * 4) + j * 4 + (k & 3)] = w[j * D + k];
}

// ---------------- aggregate: ns[n] = mean over in-neighbors of h ---------
// One wave per node. lanes: s = lane>>5 edge slot, c = lane&31 16B chunk.
__global__ __launch_bounds__(256) void aggregate(
        const float* __restrict__ h, const int* __restrict__ esrc,
        const int* __restrict__ row_ptr, const float* __restrict__ inv_deg,
        float* __restrict__ ns) {
    const int wid = blockIdx.x * 4 + (threadIdx.x >> 6);   // node id, exact 50000
    const int lane = threadIdx.x & 63;
    const int s = lane >> 5;
    const int c = lane & 31;
    const int r0 = row_ptr[wid];
    const int r1 = row_ptr[wid + 1];

    float4 acc = {0.f, 0.f, 0.f, 0.f};
    int e = r0 + s;
    for (; e + 6 < r1; e += 8) {
        int i0 = esrc[e], i1 = esrc[e + 2], i2 = esrc[e + 4], i3 = esrc[e + 6];
        float4 v0 = *(const float4*)(h + (size_t)i0 * D + c * 4);
        float4 v1 = *(const float4*)(h + (size_t)i1 * D + c * 4);
        float4 v2 = *(const float4*)(h + (size_t)i2 * D + c * 4);
        float4 v3 = *(const float4*)(h + (size_t)i3 * D + c * 4);
        acc.x += v0.x + v1.x + v2.x + v3.x;
        acc.y += v0.y + v1.y + v2.y + v3.y;
        acc.z += v0.z + v1.z + v2.z + v3.z;
        acc.w += v0.w + v1.w + v2.w + v3.w;
    }
    for (; e < r1; e += 2) {
        int i0 = esrc[e];
        float4 v0 = *(const float4*)(h + (size_t)i0 * D + c * 4);
        acc.x += v0.x; acc.y += v0.y; acc.z += v0.z; acc.w += v0.w;
    }
    // fold slot 1 into slot 0
    acc.x += __shfl_down(acc.x, 32, 64);
    acc.y += __shfl_down(acc.y, 32, 64);
    acc.z += __shfl_down(acc.z, 32, 64);
    acc.w += __shfl_down(acc.w, 32, 64);
    if (lane < 32) {
        const float idg = inv_deg[wid];
        float4 o = {acc.x * idg, acc.y * idg, acc.z * idg, acc.w * idg};
        *(float4*)(ns + (size_t)wid * D + c * 4) = o;
    }
}

// ---------------- combine: out = h@Ws^T + b + ns@Wn^T (+relu) ------------
// In-place safe (out may alias ns): rows staged to LDS before any write.
__global__ __launch_bounds__(128) void combine(
        const float* __restrict__ h, const float* __restrict__ ns,
        const float* __restrict__ Wqs, const float* __restrict__ Wqn,
        const float* __restrict__ bias, float* __restrict__ out, int do_relu) {
    const int j = threadIdx.x;
    const int n0 = blockIdx.x * NPB;
    const int q = j >> 5, c = j & 31;

    __shared__ float hs[NPB][D];
    __shared__ float nss[NPB][D];

    #pragma unroll
    for (int mg = 0; mg < 4; ++mg) {
        int m = mg * 4 + q;
        *(float4*)&hs[m][c * 4]  = *(const float4*)(h  + (size_t)(n0 + m) * D + c * 4);
        *(float4*)&nss[m][c * 4] = *(const float4*)(ns + (size_t)(n0 + m) * D + c * 4);
    }
    __syncthreads();

    float acc[NPB];
    const float bj = bias[j];
    #pragma unroll
    for (int m = 0; m < NPB; ++m) acc[m] = bj;

    #pragma unroll 2
    for (int k4 = 0; k4 < D / 4; ++k4) {
        float4 wsv = *(const float4*)(Wqs + k4 * (D * 4) + j * 4);
        float4 wnv = *(const float4*)(Wqn + k4 * (D * 4) + j * 4);
        #pragma unroll
        for (int m = 0; m < NPB; ++m) {
            float4 a = *(const float4*)&hs[m][k4 * 4];
            float4 b = *(const float4*)&nss[m][k4 * 4];
            float t = acc[m];
            t += a.x * wsv.x + a.y * wsv.y + a.z * wsv.z + a.w * wsv.w;
            t += b.x * wnv.x + b.y * wnv.y + b.z * wnv.z + b.w * wnv.w;
            acc[m] = t;
        }
    }

    #pragma unroll
    for (int m = 0; m < NPB; ++m) {
        float v = acc[m];
        if (do_relu) v = fmaxf(v, 0.f);
        out[(size_t)(n0 + m) * D + j] = v;
    }
}

extern "C" void kernel_launch(void* const* d_in, const int* in_sizes, int n_in,
                              void* d_out, int out_size, void* d_ws, size_t ws_size,
                              hipStream_t stream) {
    const float* x   = (const float*)d_in[0];
    const int* src   = (const int*)d_in[1];
    const int* dst   = (const int*)d_in[2];
    const float* Wn1 = (const float*)d_in[3];
    const float* Ws1 = (const float*)d_in[4];
    const float* b1  = (const float*)d_in[5];
    const float* Wn2 = (const float*)d_in[6];
    const float* Ws2 = (const float*)d_in[7];
    const float* b2  = (const float*)d_in[8];
    const float* Wn3 = (const float*)d_in[9];
    const float* Ws3 = (const float*)d_in[10];
    const float* b3  = (const float*)d_in[11];
    float* out = (float*)d_out;

    char* w = (char*)d_ws;
    float* inv_deg  = (float*)w;                w += 50176 * 4;
    int* counts     = (int*)w;                  w += 50176 * 4;
    int* cursor     = (int*)w;                  w += 50176 * 4;
    int* row_ptr    = (int*)w;                  w += 50432 * 4;
    int* esrc       = (int*)w;                  w += (size_t)N_EDGES * 4;
    float* Wq       = (float*)w;                w += 6 * D * D * 4;
    int* blocksums  = (int*)w;                  w += 64 * 4;
    int* blockoffs  = (int*)w;                  w += 64 * 4;
    float* bufA     = (float*)w;                // N*D floats

    const float* Wqn1 = Wq + 0 * D * D, *Wqs1 = Wq + 1 * D * D;
    const float* Wqn2 = Wq + 2 * D * D, *Wqs2 = Wq + 3 * D * D;
    const float* Wqn3 = Wq + 4 * D * D, *Wqs3 = Wq + 5 * D * D;

    // ---- CSR build ----
    zero_ints<<<(50176 + 255) / 256, 256, 0, stream>>>(counts, cursor, 50176);
    hist_kernel<<<(N_EDGES + 511) / 512, 512, 0, stream>>>(dst, counts, N_EDGES);
    scan_p1<<<NCHUNK, SCAN_BLK, 0, stream>>>(counts, row_ptr, inv_deg, blocksums);
    scan_p2<<<1, 64, 0, stream>>>(blocksums, blockoffs);
    scan_p3<<<NCHUNK, SCAN_BLK, 0, stream>>>(row_ptr, blockoffs);
    bucket_kernel<<<(N_EDGES + 511) / 512, 512, 0, stream>>>(src, dst, row_ptr, cursor,
                                                             esrc, N_EDGES);
    repack6<<<dim3(D, 6), D, 0, stream>>>(Wn1, Ws1, Wn2, Ws2, Wn3, Ws3, Wq);

    const int agrid = N_NODES / 4;    // 12500, one wave per node
    const int cgrid = N_NODES / NPB;  // 3125

    // layer 1: x -> d_out (relu); ns in bufA
    aggregate<<<agrid, 256, 0, stream>>>(x, esrc, row_ptr, inv_deg, bufA);
    combine<<<cgrid, 128, 0, stream>>>(x, bufA, Wqs1, Wqn1, b1, out, 1);

    // layer 2: d_out -> bufA (relu); ns in bufA, combine in-place over ns
    aggregate<<<agrid, 256, 0, stream>>>(out, esrc, row_ptr, inv_deg, bufA);
    combine<<<cgrid, 128, 0, stream>>>(out, bufA, Wqs2, Wqn2, b2, bufA, 1);

    // layer 3: bufA -> d_out (no relu); ns in d_out, combine in-place over ns
    aggregate<<<agrid, 256, 0, stream>>>(bufA, esrc, row_ptr, inv_deg, out);
    combine<<<cgrid, 128, 0, stream>>>(bufA, out, Wqs3, Wqn3, b3, out, 0);
}

// Round 5
// 434.985 us; speedup vs baseline: 1.9443x; 1.9443x over previous
//
#include <hip/hip_runtime.h>

// GraphSAGE 3-layer, N=50000, E=1.6M, D=128.
// R5: commute aggregation with Wn (z = h@Wn^T first, bf16 gather),
//     split-bf16 MFMA dual-GEMM, atomic-free edge scatter.

constexpr int N_NODES = 50000;
constexpr int N_EDGES = 1600000;
constexpr int D = 128;
constexpr int SCAN_BLK = 1024;
constexpr int NCHUNK = (N_NODES + SCAN_BLK - 1) / SCAN_BLK;  // 49

typedef __bf16 bf16x8 __attribute__((ext_vector_type(8)));
typedef float f32x4 __attribute__((ext_vector_type(4)));
union U8 { bf16x8 v; __bf16 e[8]; };

// ---------------- zero counts -------------------------------------------
__global__ void zero1(int* __restrict__ a, int n) {
    int i = blockIdx.x * blockDim.x + threadIdx.x;
    if (i < n) a[i] = 0;
}

// ---------------- hist + per-edge position ------------------------------
__global__ void hist_pos(const int* __restrict__ dst, int* __restrict__ counts,
                         int* __restrict__ pos, int n) {
    int e = blockIdx.x * blockDim.x + threadIdx.x;
    if (e < n) pos[e] = atomicAdd(&counts[dst[e]], 1);
}

// ---------------- scan phase 1 ------------------------------------------
__global__ __launch_bounds__(SCAN_BLK) void scan_p1(const int* __restrict__ counts,
                                                    int* __restrict__ row_ptr,
                                                    float* __restrict__ inv_deg,
                                                    int* __restrict__ blocksums) {
    __shared__ int wsum[16];
    __shared__ int wpre[16];
    const int t = threadIdx.x;
    const int i = blockIdx.x * SCAN_BLK + t;
    const int lane = t & 63, w = t >> 6;
    int v = (i < N_NODES) ? counts[i] : 0;
    int x = v;
    #pragma unroll
    for (int off = 1; off < 64; off <<= 1) {
        int tt = __shfl_up(x, off, 64);
        if (lane >= off) x += tt;
    }
    if (lane == 63) wsum[w] = x;
    __syncthreads();
    if (t < 16) {
        int s = wsum[t];
        int y = s;
        #pragma unroll
        for (int off = 1; off < 16; off <<= 1) {
            int tt = __shfl_up(y, off, 64);
            if (t >= off) y += tt;
        }
        wpre[t] = y - s;
    }
    __syncthreads();
    if (i < N_NODES) {
        row_ptr[i] = wpre[w] + (x - v);
        inv_deg[i] = 1.0f / fmaxf((float)v, 1.0f);
    }
    if (t == SCAN_BLK - 1) blocksums[blockIdx.x] = wpre[15] + wsum[15];
}

// ---------------- scan phase 2 ------------------------------------------
__global__ void scan_p2(const int* __restrict__ blocksums, int* __restrict__ blockoffs) {
    const int t = threadIdx.x;
    int v = (t < NCHUNK) ? blocksums[t] : 0;
    int x = v;
    #pragma unroll
    for (int off = 1; off < 64; off <<= 1) {
        int tt = __shfl_up(x, off, 64);
        if (t >= off) x += tt;
    }
    if (t < NCHUNK) blockoffs[t] = x - v;
}

// ---------------- scan phase 3 ------------------------------------------
__global__ __launch_bounds__(SCAN_BLK) void scan_p3(int* __restrict__ row_ptr,
                                                    const int* __restrict__ blockoffs) {
    const int i = blockIdx.x * SCAN_BLK + threadIdx.x;
    if (i < N_NODES) row_ptr[i] += blockoffs[blockIdx.x];
    if (i == 0) row_ptr[N_NODES] = N_EDGES;
}

// ---------------- atomic-free edge scatter -------------------------------
__global__ void scatter_edges(const int* __restrict__ src, const int* __restrict__ dst,
                              const int* __restrict__ pos, const int* __restrict__ row_ptr,
                              int* __restrict__ esrc, int n) {
    int e = blockIdx.x * blockDim.x + threadIdx.x;
    if (e < n) esrc[row_ptr[dst[e]] + pos[e]] = src[e];
}

// ---------------- pack W into MFMA B-fragment order, hi+lo ---------------
// B[k][j] = W[j][k]; lane holds B[k0+(lane>>4)*8+t][j0+(lane&15)], t=0..7.
// out[mat][plane][((jt*4+ks)*64+lane)*8+t], plane 0=hi, 1=lo (16384 apart).
__global__ void pack_w(const float* __restrict__ w0, const float* __restrict__ w1,
                       const float* __restrict__ w2, const float* __restrict__ w3,
                       const float* __restrict__ w4, const float* __restrict__ w5,
                       __bf16* __restrict__ outbase) {
    const float* ws[6] = {w0, w1, w2, w3, w4, w5};
    const float* W = ws[blockIdx.y];
    __bf16* o = outbase + (size_t)blockIdx.y * 32768;
    int idx = blockIdx.x * 256 + threadIdx.x;   // 0..16383
    int t = idx & 7;
    int lane = (idx >> 3) & 63;
    int ks = (idx >> 9) & 3;
    int jt = idx >> 11;
    int j = jt * 16 + (lane & 15);
    int k = ks * 32 + (lane >> 4) * 8 + t;
    float w = W[j * D + k];
    __bf16 hi = (__bf16)w;
    o[idx] = hi;
    o[16384 + idx] = (__bf16)(w - (float)hi);
}

// ---------------- dual GEMM: y = h@Ws^T + b (fp32), z = h@Wn^T (bf16) ----
// One wave per 16-node tile; split-bf16 (3 products) for both matmuls.
__global__ __launch_bounds__(256) void dual_gemm(
        const float* __restrict__ h, const __bf16* __restrict__ Bs,
        const __bf16* __restrict__ Bn, const float* __restrict__ bias,
        float* __restrict__ y_self, __bf16* __restrict__ z) {
    const int wave = threadIdx.x >> 6;
    const int lane = threadIdx.x & 63;
    const int tile = blockIdx.x * 4 + wave;
    if (tile >= N_NODES / 16) return;
    const int n0 = tile * 16;
    const int row = n0 + (lane & 15);
    const int koff = (lane >> 4) * 8;

    U8 ahi[4], alo[4];
    #pragma unroll
    for (int ks = 0; ks < 4; ++ks) {
        const float* p = h + (size_t)row * D + ks * 32 + koff;
        float f[8];
        *(f32x4*)&f[0] = *(const f32x4*)p;
        *(f32x4*)&f[4] = *(const f32x4*)(p + 4);
        #pragma unroll
        for (int t = 0; t < 8; ++t) {
            __bf16 hi = (__bf16)f[t];
            ahi[ks].e[t] = hi;
            alo[ks].e[t] = (__bf16)(f[t] - (float)hi);
        }
    }

    const int jcol = lane & 15;
    const int r0 = (lane >> 4) * 4;

    #pragma unroll 2
    for (int jt = 0; jt < 8; ++jt) {
        f32x4 accS = {0.f, 0.f, 0.f, 0.f};
        f32x4 accN = {0.f, 0.f, 0.f, 0.f};
        #pragma unroll
        for (int ks = 0; ks < 4; ++ks) {
            const size_t off = (((size_t)jt * 4 + ks) * 64 + lane) * 8;
            bf16x8 wsh = *(const bf16x8*)(Bs + off);
            bf16x8 wsl = *(const bf16x8*)(Bs + 16384 + off);
            bf16x8 wnh = *(const bf16x8*)(Bn + off);
            bf16x8 wnl = *(const bf16x8*)(Bn + 16384 + off);
            accS = __builtin_amdgcn_mfma_f32_16x16x32_bf16(ahi[ks].v, wsh, accS, 0, 0, 0);
            accS = __builtin_amdgcn_mfma_f32_16x16x32_bf16(alo[ks].v, wsh, accS, 0, 0, 0);
            accS = __builtin_amdgcn_mfma_f32_16x16x32_bf16(ahi[ks].v, wsl, accS, 0, 0, 0);
            accN = __builtin_amdgcn_mfma_f32_16x16x32_bf16(ahi[ks].v, wnh, accN, 0, 0, 0);
            accN = __builtin_amdgcn_mfma_f32_16x16x32_bf16(alo[ks].v, wnh, accN, 0, 0, 0);
            accN = __builtin_amdgcn_mfma_f32_16x16x32_bf16(ahi[ks].v, wnl, accN, 0, 0, 0);
        }
        const int j = jt * 16 + jcol;
        const float bj = bias[j];
        #pragma unroll
        for (int r = 0; r < 4; ++r) {
            const size_t n = n0 + r0 + r;
            y_self[n * D + j] = accS[r] + bj;
            z[n * D + j] = (__bf16)accN[r];
        }
    }
}

// ---------------- aggregate z (bf16) + add y_self (+relu) ----------------
// One wave per node; 4 edge slots x 16 lanes x 16B chunks of the 256B row.
__global__ __launch_bounds__(256) void agg_add(
        const __bf16* __restrict__ z, const int* __restrict__ esrc,
        const int* __restrict__ row_ptr, const float* __restrict__ inv_deg,
        const float* __restrict__ y_self, float* __restrict__ out, int do_relu) {
    const int n = blockIdx.x * 4 + (threadIdx.x >> 6);
    const int lane = threadIdx.x & 63;
    const int s = lane >> 4;
    const int c = lane & 15;
    const int r0 = row_ptr[n], r1 = row_ptr[n + 1];

    float acc[8] = {0.f, 0.f, 0.f, 0.f, 0.f, 0.f, 0.f, 0.f};
    int e = r0 + s;
    for (; e + 12 < r1; e += 16) {
        int i0 = esrc[e], i1 = esrc[e + 4], i2 = esrc[e + 8], i3 = esrc[e + 12];
        U8 v0, v1, v2, v3;
        v0.v = *(const bf16x8*)(z + (size_t)i0 * D + c * 8);
        v1.v = *(const bf16x8*)(z + (size_t)i1 * D + c * 8);
        v2.v = *(const bf16x8*)(z + (size_t)i2 * D + c * 8);
        v3.v = *(const bf16x8*)(z + (size_t)i3 * D + c * 8);
        #pragma unroll
        for (int t = 0; t < 8; ++t)
            acc[t] += ((float)v0.e[t] + (float)v1.e[t]) + ((float)v2.e[t] + (float)v3.e[t]);
    }
    for (; e < r1; e += 4) {
        U8 v0;
        v0.v = *(const bf16x8*)(z + (size_t)esrc[e] * D + c * 8);
        #pragma unroll
        for (int t = 0; t < 8; ++t) acc[t] += (float)v0.e[t];
    }
    #pragma unroll
    for (int t = 0; t < 8; ++t) acc[t] += __shfl_down(acc[t], 32, 64);
    #pragma unroll
    for (int t = 0; t < 8; ++t) acc[t] += __shfl_down(acc[t], 16, 64);

    if (lane < 16) {
        const float idg = inv_deg[n];
        const float* yp = y_self + (size_t)n * D + c * 8;
        f32x4 y0 = *(const f32x4*)yp;
        f32x4 y1 = *(const f32x4*)(yp + 4);
        float o[8];
        #pragma unroll
        for (int t = 0; t < 4; ++t) o[t] = y0[t] + acc[t] * idg;
        #pragma unroll
        for (int t = 0; t < 4; ++t) o[4 + t] = y1[t] + acc[4 + t] * idg;
        if (do_relu) {
            #pragma unroll
            for (int t = 0; t < 8; ++t) o[t] = fmaxf(o[t], 0.f);
        }
        float* op = out + (size_t)n * D + c * 8;
        *(f32x4*)op = *(f32x4*)&o[0];
        *(f32x4*)(op + 4) = *(f32x4*)&o[4];
    }
}

extern "C" void kernel_launch(void* const* d_in, const int* in_sizes, int n_in,
                              void* d_out, int out_size, void* d_ws, size_t ws_size,
                              hipStream_t stream) {
    const float* x   = (const float*)d_in[0];
    const int* src   = (const int*)d_in[1];
    const int* dst   = (const int*)d_in[2];
    const float* Wn1 = (const float*)d_in[3];
    const float* Ws1 = (const float*)d_in[4];
    const float* b1  = (const float*)d_in[5];
    const float* Wn2 = (const float*)d_in[6];
    const float* Ws2 = (const float*)d_in[7];
    const float* b2  = (const float*)d_in[8];
    const float* Wn3 = (const float*)d_in[9];
    const float* Ws3 = (const float*)d_in[10];
    const float* b3  = (const float*)d_in[11];
    float* out = (float*)d_out;

    char* w = (char*)d_ws;
    float* inv_deg  = (float*)w;                w += 50176 * 4;
    int* counts     = (int*)w;                  w += 50176 * 4;
    int* row_ptr    = (int*)w;                  w += 50432 * 4;
    int* blocksums  = (int*)w;                  w += 64 * 4;
    int* blockoffs  = (int*)w;                  w += 64 * 4;
    int* esrc       = (int*)w;                  w += (size_t)N_EDGES * 4;
    __bf16* Bpk     = (__bf16*)w;               w += 6 * 32768 * 2;
    __bf16* zbuf    = (__bf16*)w;               w += (size_t)50176 * D * 2;  // aliases pos
    float* bufA     = (float*)w;                // N*D floats

    int* pos = (int*)zbuf;   // pos[] only needed before zbuf is first written

    const __bf16* PWs1 = Bpk + 0 * 32768, *PWn1 = Bpk + 1 * 32768;
    const __bf16* PWs2 = Bpk + 2 * 32768, *PWn2 = Bpk + 3 * 32768;
    const __bf16* PWs3 = Bpk + 4 * 32768, *PWn3 = Bpk + 5 * 32768;

    // ---- CSR build (atomic-free scatter) ----
    zero1<<<(50176 + 255) / 256, 256, 0, stream>>>(counts, 50176);
    hist_pos<<<(N_EDGES + 511) / 512, 512, 0, stream>>>(dst, counts, pos, N_EDGES);
    scan_p1<<<NCHUNK, SCAN_BLK, 0, stream>>>(counts, row_ptr, inv_deg, blocksums);
    scan_p2<<<1, 64, 0, stream>>>(blocksums, blockoffs);
    scan_p3<<<NCHUNK, SCAN_BLK, 0, stream>>>(row_ptr, blockoffs);
    scatter_edges<<<(N_EDGES + 511) / 512, 512, 0, stream>>>(src, dst, pos, row_ptr,
                                                             esrc, N_EDGES);
    // ---- pack weights (order: Ws1,Wn1,Ws2,Wn2,Ws3,Wn3) ----
    pack_w<<<dim3(64, 6), 256, 0, stream>>>(Ws1, Wn1, Ws2, Wn2, Ws3, Wn3, Bpk);

    const int ggrid = (N_NODES / 16 + 3) / 4;   // 782 blocks x 4 waves
    const int agrid = N_NODES / 4;              // 12500 blocks x 4 waves

    // layer 1: h=x -> bufA (relu)
    dual_gemm<<<ggrid, 256, 0, stream>>>(x, PWs1, PWn1, b1, bufA, zbuf);
    agg_add<<<agrid, 256, 0, stream>>>(zbuf, esrc, row_ptr, inv_deg, bufA, bufA, 1);

    // layer 2: h=bufA -> d_out (relu)
    dual_gemm<<<ggrid, 256, 0, stream>>>(bufA, PWs2, PWn2, b2, out, zbuf);
    agg_add<<<agrid, 256, 0, stream>>>(zbuf, esrc, row_ptr, inv_deg, out, out, 1);

    // layer 3: h=d_out -> d_out (no relu), y_self staged in bufA
    dual_gemm<<<ggrid, 256, 0, stream>>>(out, PWs3, PWn3, b3, bufA, zbuf);
    agg_add<<<agrid, 256, 0, stream>>>(zbuf, esrc, row_ptr, inv_deg, bufA, out, 0);
}